// Round 2
// baseline (2887.467 us; speedup 1.0000x reference)
//
#include <hip/hip_runtime.h>
#include <hip/hip_bf16.h>
#include <cstdint>

#define N_NODES 50000
#define N_PAIRS 800000
#define NHEADS 4
#define NF 256
#define HD 64

typedef unsigned short ushort_t;

__device__ __forceinline__ float bfu(unsigned int lo16) {
    union { unsigned int u; float f; } c; c.u = lo16 << 16; return c.f;
}
__device__ __forceinline__ ushort_t f2bf(float f) {
    union { float f; unsigned int u; } c; c.f = f;
    unsigned int u = c.u;
    unsigned int r = (u + 0x7fffu + ((u >> 16) & 1u)) >> 16;
    return (ushort_t)r;
}

// ---------------- Projection: q,k,v = per-head x @ W^T (fp32 in, bf16 out) --------
// block = 256 threads (wave = head, lane = output elem e).
// Each thread holds its 3x64 fp32 weight rows in VGPRs; x staged via LDS.
__global__ __launch_bounds__(256, 2) void proj_kernel(
    const float* __restrict__ x,
    const float* __restrict__ Wq, const float* __restrict__ Wk,
    const float* __restrict__ Wv,
    ushort_t* __restrict__ q, ushort_t* __restrict__ k, ushort_t* __restrict__ v)
{
    const int t = threadIdx.x;
    const int h = t >> 6;
    const int e = t & 63;

    float wq[64], wk[64], wv[64];
    {
        const float4* rq = (const float4*)(Wq + (size_t)(h * 64 + e) * 64);
        const float4* rk = (const float4*)(Wk + (size_t)(h * 64 + e) * 64);
        const float4* rv = (const float4*)(Wv + (size_t)(h * 64 + e) * 64);
#pragma unroll
        for (int r = 0; r < 16; ++r) {
            float4 a = rq[r];
            wq[r*4+0]=a.x; wq[r*4+1]=a.y; wq[r*4+2]=a.z; wq[r*4+3]=a.w;
            float4 b = rk[r];
            wk[r*4+0]=b.x; wk[r*4+1]=b.y; wk[r*4+2]=b.z; wk[r*4+3]=b.w;
            float4 c = rv[r];
            wv[r*4+0]=c.x; wv[r*4+1]=c.y; wv[r*4+2]=c.z; wv[r*4+3]=c.w;
        }
    }

    __shared__ float xs[8][256];     // 8 nodes x 256 features
    const int n0 = blockIdx.x * 8;   // 50000 / 8 = 6250 exactly
    {
        const float4* src = (const float4*)(x + (size_t)n0 * 256);
        float4* dst = (float4*)(&xs[0][0]);
        dst[t]       = src[t];
        dst[t + 256] = src[t + 256];
    }
    __syncthreads();

#pragma unroll 1
    for (int s = 0; s < 8; ++s) {
        const float4* xr = (const float4*)(&xs[s][h * 64]);
        float aq = 0.f, ak = 0.f, av = 0.f;
#pragma unroll
        for (int d4 = 0; d4 < 16; ++d4) {
            float4 xv = xr[d4];
            aq = fmaf(wq[d4*4+0], xv.x, aq); ak = fmaf(wk[d4*4+0], xv.x, ak); av = fmaf(wv[d4*4+0], xv.x, av);
            aq = fmaf(wq[d4*4+1], xv.y, aq); ak = fmaf(wk[d4*4+1], xv.y, ak); av = fmaf(wv[d4*4+1], xv.y, av);
            aq = fmaf(wq[d4*4+2], xv.z, aq); ak = fmaf(wk[d4*4+2], xv.z, ak); av = fmaf(wv[d4*4+2], xv.z, av);
            aq = fmaf(wq[d4*4+3], xv.w, aq); ak = fmaf(wk[d4*4+3], xv.w, ak); av = fmaf(wv[d4*4+3], xv.w, av);
        }
        const size_t o = (size_t)(n0 + s) * 256 + t;   // t == h*64+e
        q[o] = f2bf(aq);
        k[o] = f2bf(ak);
        v[o] = f2bf(av);
    }
}

// ---------------- CSR build ----------------
__global__ void hist_kernel(const int* __restrict__ idx_i, int* __restrict__ counts) {
    int e = blockIdx.x * 256 + threadIdx.x;    // 3125*256 == 800000 exactly
    atomicAdd(&counts[idx_i[e]], 1);
}

__global__ void scan_kernel(const int* __restrict__ counts, int* __restrict__ offsets, int n) {
    __shared__ int s[1024];
    const int t = threadIdx.x;
    int carry = 0;
    for (int base = 0; base < n; base += 1024) {
        int val = (base + t < n) ? counts[base + t] : 0;
        s[t] = val;
        __syncthreads();
        for (int off = 1; off < 1024; off <<= 1) {
            int add = (t >= off) ? s[t - off] : 0;
            __syncthreads();
            s[t] += add;
            __syncthreads();
        }
        if (base + t < n) offsets[base + t] = carry + s[t] - val;  // exclusive
        int tot = s[1023];
        __syncthreads();
        carry += tot;
    }
    if (t == 0) offsets[n] = carry;
}

__global__ void scatter_kernel(const int* __restrict__ idx_i, int* __restrict__ cursor,
                               int* __restrict__ el) {
    int e = blockIdx.x * 256 + threadIdx.x;
    int pos = atomicAdd(&cursor[idx_i[e]], 1);
    el[pos] = e;
}

// ---------------- Fused edge phase: alpha + weighted scatter, atomic-free ---------
// block = node, wave = head, lane = feature within head.
__global__ __launch_bounds__(256) void gather_kernel(
    const float* __restrict__ w_ij, const int* __restrict__ idx_j,
    const float* __restrict__ phi,
    const ushort_t* __restrict__ q, const ushort_t* __restrict__ kk,
    const ushort_t* __restrict__ vv,
    const int* __restrict__ offsets, const int* __restrict__ el,
    float* __restrict__ out)
{
    const int n = blockIdx.x;
    const int t = threadIdx.x;
    const float qv = bfu(q[(size_t)n * 256 + t]);
    const int s0 = offsets[n], s1 = offsets[n + 1];

    __shared__ int ew[256];
    __shared__ int ej[256];
    __shared__ float eph[256];

    float acc = 0.f;
    for (int base = s0; base < s1; base += 256) {
        int cnt = min(256, s1 - base);
        if (t < cnt) {
            int e = el[base + t];
            ew[t] = e;
            ej[t] = idx_j[e];
            eph[t] = phi[e] * 0.125f;   // 1/sqrt(64)
        }
        __syncthreads();
        for (int i = 0; i < cnt; ++i) {
            const int e = ew[i];
            const int j = ej[i];
            float w  = w_ij[(size_t)e * 256 + t];
            float kj = bfu(kk[(size_t)j * 256 + t]);
            float p = qv * w * kj;
#pragma unroll
            for (int m = 32; m >= 1; m >>= 1) p += __shfl_xor(p, m, 64);
            float vva = bfu(vv[(size_t)j * 256 + t]);
            acc = fmaf(p * eph[i], vva, acc);
        }
        __syncthreads();
    }
    out[(size_t)n * 256 + t] = acc;
}

// ---------------- launch ----------------
extern "C" void kernel_launch(void* const* d_in, const int* in_sizes, int n_in,
                              void* d_out, int out_size, void* d_ws, size_t ws_size,
                              hipStream_t stream) {
    const float* x    = (const float*)d_in[0];
    const float* w_ij = (const float*)d_in[1];
    const int* idx_i  = (const int*)d_in[2];
    const int* idx_j  = (const int*)d_in[3];
    const float* phi  = (const float*)d_in[4];
    const float* Wq   = (const float*)d_in[5];
    const float* Wk   = (const float*)d_in[6];
    const float* Wv   = (const float*)d_in[7];
    float* out = (float*)d_out;

    char* ws = (char*)d_ws;
    ushort_t* q   = (ushort_t*)(ws + 0);           // 25.6 MB
    ushort_t* k   = (ushort_t*)(ws + 25600000);    // 25.6 MB
    ushort_t* v   = (ushort_t*)(ws + 51200000);    // 25.6 MB
    int* counts   = (int*)(ws + 76800000);         // 200 KB
    int* offsets  = (int*)(ws + 77000192);         // 200 KB (+1 entry)
    int* cursor   = (int*)(ws + 77200896);         // 200 KB
    int* el       = (int*)(ws + 77401088);         // 3.2 MB

    hipMemsetAsync(counts, 0, N_NODES * sizeof(int), stream);
    proj_kernel<<<6250, 256, 0, stream>>>(x, Wq, Wk, Wv, q, k, v);
    hist_kernel<<<3125, 256, 0, stream>>>(idx_i, counts);
    scan_kernel<<<1, 1024, 0, stream>>>(counts, offsets, N_NODES);
    hipMemcpyAsync(cursor, offsets, N_NODES * sizeof(int), hipMemcpyDeviceToDevice, stream);
    scatter_kernel<<<3125, 256, 0, stream>>>(idx_i, cursor, el);
    gather_kernel<<<N_NODES, 256, 0, stream>>>(w_ij, idx_j, phi, q, k, v, offsets, el, out);
}